// Round 2
// baseline (357.281 us; speedup 1.0000x reference)
//
#include <hip/hip_runtime.h>
#include <stdint.h>

#define GS   512   // graph size N
#define CF   128   // C_IN = C_OUT
#define XROW 640   // GS + CF
#define NB   128   // batch

typedef __attribute__((ext_vector_type(4))) float          f32x4;
typedef __attribute__((ext_vector_type(8))) short          s16x8;
typedef __attribute__((ext_vector_type(4))) unsigned short u16x4;
typedef __attribute__((ext_vector_type(8))) unsigned short u16x8;

__device__ __forceinline__ unsigned short f2bf(float f) {
    unsigned u = __builtin_bit_cast(unsigned, f);
    u = (u + 0x7fffu + ((u >> 16) & 1u)) >> 16;   // RNE
    return (unsigned short)u;
}
__device__ __forceinline__ float bf2f(unsigned short h) {
    unsigned u = ((unsigned)h) << 16;
    return __builtin_bit_cast(float, u);
}
__device__ __forceinline__ void glds16(const void* g, void* l) {
    __builtin_amdgcn_global_load_lds(
        (const __attribute__((address_space(1))) void*)g,
        (__attribute__((address_space(3))) void*)l, 16, 0, 0);
}

// ---------------------------------------------------------------------------
// k0: W (fp32 [c][f]) -> WTst bf16 in k2's fragment-native order:
//     WTst[((ks*4+lk)*128 + f)*8 + j] = bf16(W[ks*32+lk*8+j][f])
// ---------------------------------------------------------------------------
__global__ __launch_bounds__(256) void k0_wt(const float* __restrict__ W,
                                             unsigned short* __restrict__ WTst) {
    const int e = blockIdx.x * 256 + threadIdx.x;   // 0..16383
    const int j = e & 7, f = (e >> 3) & 127, q = e >> 10;   // q = ks*4+lk
    const int c = (q >> 2) * 32 + (q & 3) * 8 + j;
    WTst[e] = f2bf(W[c * CF + f]);
}

// ---------------------------------------------------------------------------
// k1: per row: deg -> dis = rsqrt(deg); fp32 A copy to out[:, :, :512];
//     bf16 A written in k3's MFMA-fragment order:
//     Abf window (b, rt=row/16) 16KB: byte = kt*1024 + (lk*16 + lr)*16
// one wave per row, 2 rows per wave (block covers 8 consecutive rows so
// 128-B L2 lines of Abf are fully written within one block)
// ---------------------------------------------------------------------------
__global__ __launch_bounds__(256) void k1_pre(const float* __restrict__ X,
                                              float* __restrict__ out,
                                              float* __restrict__ dis,
                                              unsigned short* __restrict__ Abf) {
    const int wv = threadIdx.x >> 6, l = threadIdx.x & 63;
    const int gbase = blockIdx.x << 3;
#pragma unroll
    for (int p = 0; p < 2; ++p) {
        const int gr = gbase + wv + (p << 2);
        const f32x4* rp = (const f32x4*)(X + (size_t)gr * XROW);
        f32x4* op = (f32x4*)(out + (size_t)gr * XROW);
        f32x4 v0 = rp[2 * l], v1 = rp[2 * l + 1];
        op[2 * l] = v0; op[2 * l + 1] = v1;
        u16x8 o;
        o[0] = f2bf(v0[0]); o[1] = f2bf(v0[1]); o[2] = f2bf(v0[2]); o[3] = f2bf(v0[3]);
        o[4] = f2bf(v1[0]); o[5] = f2bf(v1[1]); o[6] = f2bf(v1[2]); o[7] = f2bf(v1[3]);
        const int b = gr >> 9, n = gr & (GS - 1);
        const int rt = n >> 4, lr = n & 15;
        *(u16x8*)((char*)Abf + (((size_t)(b * 32 + rt)) << 14) + (l << 8) + (lr << 4)) = o;
        float s = (v0[0] + v0[1]) + (v0[2] + v0[3]) + (v1[0] + v1[1]) + (v1[2] + v1[3]);
#pragma unroll
        for (int off = 32; off; off >>= 1) s += __shfl_xor(s, off, 64);
        if (l == 0) dis[gr] = (s > 0.f) ? (1.f / sqrtf(s)) : 0.f;
    }
}

// ---------------------------------------------------------------------------
// k2: fwdT = bf16( dis[m] * (feat[m,:] @ W) ), written in k3's staging-linear
//     order: [b][kt(16)][lk(4)][f(128)][8 m-values]
// block = 64 m-rows x 128 f; waves 2x2 of (32m x 64f)
// ---------------------------------------------------------------------------
__global__ __launch_bounds__(256) void k2_featw(const float* __restrict__ X,
                                                const unsigned short* __restrict__ WTst,
                                                const float* __restrict__ dis,
                                                unsigned short* __restrict__ fwdT) {
    __shared__ __align__(16) float sf[64 * 128];            // feat tile (chunk-swizzled)
    __shared__ __align__(16) unsigned short swt[16384];     // W^T frags, 32KB
    const int t = threadIdx.x, l = t & 63, wv = t >> 6;
    const int m0 = blockIdx.x << 6;
    const int b = m0 >> 9, ml0 = m0 & (GS - 1);

    const char* fb = (const char*)(X + (size_t)m0 * XROW + GS);
    char* sfb = (char*)sf;
#pragma unroll
    for (int it = 0; it < 8; ++it) {                         // feat: 64 rows x 32 chunks
        int chunk = it * 256 + t;
        int row = chunk >> 5, c16 = chunk & 31;
        int c16s = c16 ^ (row & 7);                          // pre-swizzled source
        glds16(fb + (size_t)row * (XROW * 4) + c16s * 16, sfb + it * 4096 + wv * 1024);
    }
#pragma unroll
    for (int it = 0; it < 8; ++it)                           // W^T frags: linear
        glds16((const char*)WTst + it * 4096 + wv * 1024 + l * 16,
               (char*)swt + it * 4096 + wv * 1024);
    __syncthreads();

    const int wr = wv >> 1, wc = wv & 1, lr = l & 15, lk = l >> 4;
    f32x4 acc[2][4];
#pragma unroll
    for (int i = 0; i < 2; ++i)
#pragma unroll
        for (int j = 0; j < 4; ++j)
#pragma unroll
            for (int r = 0; r < 4; ++r) acc[i][j][r] = 0.f;

#pragma unroll
    for (int ks = 0; ks < 4; ++ks) {
        s16x8 af[2];
#pragma unroll
        for (int i = 0; i < 2; ++i) {
            int row = (wr << 5) + (i << 4) + lr;
            int cb = (ks << 3) + (lk << 1);
            int c0 = cb ^ (row & 7), c1 = (cb + 1) ^ (row & 7);
            f32x4 x0 = *(const f32x4*)&sf[row * 128 + (c0 << 2)];
            f32x4 x1 = *(const f32x4*)&sf[row * 128 + (c1 << 2)];
            s16x8 a;
            a[0] = f2bf(x0[0]); a[1] = f2bf(x0[1]); a[2] = f2bf(x0[2]); a[3] = f2bf(x0[3]);
            a[4] = f2bf(x1[0]); a[5] = f2bf(x1[1]); a[6] = f2bf(x1[2]); a[7] = f2bf(x1[3]);
            af[i] = a;
        }
#pragma unroll
        for (int j = 0; j < 4; ++j) {
            int f = (wc << 6) + (j << 4) + lr;
            s16x8 bfr = *(const s16x8*)&swt[((((ks << 2) | lk) << 7) | f) << 3];
#pragma unroll
            for (int i = 0; i < 2; ++i)
                acc[i][j] = __builtin_amdgcn_mfma_f32_16x16x32_bf16(af[i], bfr, acc[i][j], 0, 0, 0);
        }
    }

    // epilogue: scale by dis[m], store to fwdT in k3 order
#pragma unroll
    for (int i = 0; i < 2; ++i) {
        int mr = (wr << 5) + (i << 4) + (lk << 2);
        f32x4 d4 = *(const f32x4*)&dis[m0 + mr];
        int mg = ml0 + mr;
        int ktm = mg >> 5, q3 = (mg >> 3) & 3, jm = mg & 7;
#pragma unroll
        for (int j = 0; j < 4; ++j) {
            int f = (wc << 6) + (j << 4) + lr;
            u16x4 o;
            o[0] = f2bf(d4[0] * acc[i][j][0]);
            o[1] = f2bf(d4[1] * acc[i][j][1]);
            o[2] = f2bf(d4[2] * acc[i][j][2]);
            o[3] = f2bf(d4[3] * acc[i][j][3]);
            *(u16x4*)((char*)fwdT + ((size_t)b << 17) + (((ktm << 2) | q3) << 11)
                      + (f << 4) + (jm << 1)) = o;
        }
    }
}

// ---------------------------------------------------------------------------
// k3: out[b,n,512+f] = relu( dis[n] * (A[n,:] @ featWD[:,f] + featWD[n,f]) )
// block = 64 rows x 128 f; 4 waves each own 16 rows x 128 f.
// A: direct global->VGPR (fragment-order Abf, 1 dwordx4/kt, prefetch 1 ahead)
// B: double-buffered LDS via linear glds16, conflict-free [lk][f][8] reads
// ---------------------------------------------------------------------------
__global__ __launch_bounds__(256) void k3_gcn(const unsigned short* __restrict__ Abf,
                                              const float* __restrict__ dis,
                                              const unsigned short* __restrict__ fwdT,
                                              float* __restrict__ out) {
    __shared__ __align__(16) unsigned short sb[2][4096];    // 8KB per buf
    const int t = threadIdx.x, l = t & 63, wv = t >> 6, lr = l & 15, lk = l >> 4;
    const int b = blockIdx.x >> 3, bm0 = (blockIdx.x & 7) << 6;
    const char* Bt = (const char*)fwdT + ((size_t)b << 17);
    const int rt = (bm0 >> 4) + wv;
    const char* Ab = (const char*)Abf + (((size_t)(b * 32 + rt)) << 14);

    auto stage = [&](int buf, int kt) {
#pragma unroll
        for (int it = 0; it < 2; ++it)
            glds16(Bt + (kt << 13) + it * 4096 + wv * 1024 + l * 16,
                   (char*)sb[buf] + it * 4096 + wv * 1024);
    };

    f32x4 acc[8];
#pragma unroll
    for (int j = 0; j < 8; ++j)
#pragma unroll
        for (int r = 0; r < 4; ++r) acc[j][r] = 0.f;

    stage(0, 0);
    s16x8 a = *(const s16x8*)(Ab + (l << 4));
    int cur = 0;
    for (int kt = 0; kt < 16; ++kt) {
        __syncthreads();                                    // drains staging vmcnt
        if (kt < 15) stage(cur ^ 1, kt + 1);
        s16x8 an = a;
        if (kt < 15) an = *(const s16x8*)(Ab + ((kt + 1) << 10) + (l << 4));
#pragma unroll
        for (int j = 0; j < 8; ++j) {
            s16x8 bfr = *(const s16x8*)&sb[cur][(lk << 10) + (j << 7) + (lr << 3)];
            acc[j] = __builtin_amdgcn_mfma_f32_16x16x32_bf16(a, bfr, acc[j], 0, 0, 0);
        }
        a = an; cur ^= 1;
    }

    // epilogue: + identity featWD[n,f], * dis[n], relu, store fp32
    const int n0 = bm0 + (wv << 4) + (lk << 2);             // base of 4 rows
    f32x4 d4 = *(const f32x4*)&dis[(b << 9) + n0];
    const int ktm = n0 >> 5, q3 = (n0 >> 3) & 3, jm = n0 & 7;
#pragma unroll
    for (int j = 0; j < 8; ++j) {
        int f = (j << 4) + lr;
        u16x4 fw = *(const u16x4*)(Bt + (((ktm << 2) | q3) << 11) + (f << 4) + (jm << 1));
        float* ob = out + ((size_t)(b * GS + n0)) * XROW + GS + f;
#pragma unroll
        for (int r = 0; r < 4; ++r) {
            float v = d4[r] * (acc[j][r] + bf2f(fw[r]));
            ob[(size_t)r * XROW] = v > 0.f ? v : 0.f;
        }
    }
}

extern "C" void kernel_launch(void* const* d_in, const int* in_sizes, int n_in,
                              void* d_out, int out_size, void* d_ws, size_t ws_size,
                              hipStream_t stream) {
    const float* X = (const float*)d_in[0];
    const float* W = (const float*)d_in[1];
    float* out = (float*)d_out;
    // ws layout (bytes):
    float*          dis  = (float*)d_ws;                                  // 262144
    unsigned short* WTst = (unsigned short*)((char*)d_ws + 262144);       // 32768
    unsigned short* fwdT = (unsigned short*)((char*)d_ws + 294912);       // 16 MiB
    unsigned short* Abf  = (unsigned short*)((char*)d_ws + 17072128);     // 64 MiB

    hipLaunchKernelGGL(k0_wt,   dim3(64),   dim3(256), 0, stream, W, WTst);
    hipLaunchKernelGGL(k1_pre,  dim3(NB * GS / 8),  dim3(256), 0, stream, X, out, dis, Abf);
    hipLaunchKernelGGL(k2_featw, dim3(NB * GS / 64), dim3(256), 0, stream, X, WTst, dis, fwdT);
    hipLaunchKernelGGL(k3_gcn,  dim3(NB * GS / 64), dim3(256), 0, stream, Abf, dis, fwdT, out);
}

// Round 3
// 335.392 us; speedup vs baseline: 1.0653x; 1.0653x over previous
//
#include <hip/hip_runtime.h>
#include <stdint.h>

#define GS   512   // graph size N
#define CF   128   // C_IN = C_OUT
#define XROW 640   // GS + CF
#define NB   128   // batch

typedef __attribute__((ext_vector_type(4))) float          f32x4;
typedef __attribute__((ext_vector_type(8))) short          s16x8;
typedef __attribute__((ext_vector_type(4))) unsigned short u16x4;
typedef __attribute__((ext_vector_type(8))) unsigned short u16x8;

__device__ __forceinline__ unsigned short f2bf(float f) {
    unsigned u = __builtin_bit_cast(unsigned, f);
    u = (u + 0x7fffu + ((u >> 16) & 1u)) >> 16;   // RNE
    return (unsigned short)u;
}
__device__ __forceinline__ float bf2f(unsigned short h) {
    unsigned u = ((unsigned)h) << 16;
    return __builtin_bit_cast(float, u);
}
__device__ __forceinline__ void glds16(const void* g, void* l) {
    __builtin_amdgcn_global_load_lds(
        (const __attribute__((address_space(1))) void*)g,
        (__attribute__((address_space(3))) void*)l, 16, 0, 0);
}

// ---------------------------------------------------------------------------
// k0: W (fp32 [c][f]) -> WTst bf16 in k2's fragment-native order:
//     WTst[((ks*4+lk)*128 + f)*8 + j] = bf16(W[ks*32+lk*8+j][f])
// ---------------------------------------------------------------------------
__global__ __launch_bounds__(256) void k0_wt(const float* __restrict__ W,
                                             unsigned short* __restrict__ WTst) {
    const int e = blockIdx.x * 256 + threadIdx.x;   // 0..16383
    const int j = e & 7, f = (e >> 3) & 127, q = e >> 10;   // q = ks*4+lk
    const int c = (q >> 2) * 32 + (q & 3) * 8 + j;
    WTst[e] = f2bf(W[c * CF + f]);
}

// ---------------------------------------------------------------------------
// k1: per row: deg -> dis = rsqrt(deg); fp32 A copy to out[:, :, :512];
//     bf16 A written LINEAR row-major: Abf[b][n][k] (lane l -> k=8l..8l+7,
//     store at row*1024 + l*16 -> fully coalesced 1KB per wave-row)
// ---------------------------------------------------------------------------
__global__ __launch_bounds__(256) void k1_pre(const float* __restrict__ X,
                                              float* __restrict__ out,
                                              float* __restrict__ dis,
                                              unsigned short* __restrict__ Abf) {
    const int wv = threadIdx.x >> 6, l = threadIdx.x & 63;
    const int gbase = blockIdx.x << 3;
#pragma unroll
    for (int p = 0; p < 2; ++p) {
        const int gr = gbase + wv + (p << 2);                 // global row b*512+n
        const f32x4* rp = (const f32x4*)(X + (size_t)gr * XROW);
        f32x4* op = (f32x4*)(out + (size_t)gr * XROW);
        f32x4 v0 = rp[2 * l], v1 = rp[2 * l + 1];
        op[2 * l] = v0; op[2 * l + 1] = v1;
        u16x8 o;
        o[0] = f2bf(v0[0]); o[1] = f2bf(v0[1]); o[2] = f2bf(v0[2]); o[3] = f2bf(v0[3]);
        o[4] = f2bf(v1[0]); o[5] = f2bf(v1[1]); o[6] = f2bf(v1[2]); o[7] = f2bf(v1[3]);
        *(u16x8*)((char*)Abf + ((size_t)gr << 10) + (l << 4)) = o;
        float s = (v0[0] + v0[1]) + (v0[2] + v0[3]) + (v1[0] + v1[1]) + (v1[2] + v1[3]);
#pragma unroll
        for (int off = 32; off; off >>= 1) s += __shfl_xor(s, off, 64);
        if (l == 0) dis[gr] = (s > 0.f) ? (1.f / sqrtf(s)) : 0.f;
    }
}

// ---------------------------------------------------------------------------
// k2: fwdT = bf16( dis[m] * (feat[m,:] @ W) ), written in k3's staging-linear
//     order: [b][kt(16)][lk(4)][f(128)][8 m-values]
// block = 64 m-rows x 128 f; waves 2x2 of (32m x 64f)
// ---------------------------------------------------------------------------
__global__ __launch_bounds__(256) void k2_featw(const float* __restrict__ X,
                                                const unsigned short* __restrict__ WTst,
                                                const float* __restrict__ dis,
                                                unsigned short* __restrict__ fwdT) {
    __shared__ __align__(16) float sf[64 * 128];            // feat tile (chunk-swizzled)
    __shared__ __align__(16) unsigned short swt[16384];     // W^T frags, 32KB
    const int t = threadIdx.x, l = t & 63, wv = t >> 6;
    const int m0 = blockIdx.x << 6;
    const int b = m0 >> 9, ml0 = m0 & (GS - 1);

    const char* fb = (const char*)(X + (size_t)m0 * XROW + GS);
    char* sfb = (char*)sf;
#pragma unroll
    for (int it = 0; it < 8; ++it) {                         // feat: 64 rows x 32 chunks
        int chunk = it * 256 + t;
        int row = chunk >> 5, c16 = chunk & 31;
        int c16s = c16 ^ (row & 7);                          // pre-swizzled source
        glds16(fb + (size_t)row * (XROW * 4) + c16s * 16, sfb + it * 4096 + wv * 1024);
    }
#pragma unroll
    for (int it = 0; it < 8; ++it)                           // W^T frags: linear
        glds16((const char*)WTst + it * 4096 + wv * 1024 + l * 16,
               (char*)swt + it * 4096 + wv * 1024);
    __syncthreads();

    const int wr = wv >> 1, wc = wv & 1, lr = l & 15, lk = l >> 4;
    f32x4 acc[2][4];
#pragma unroll
    for (int i = 0; i < 2; ++i)
#pragma unroll
        for (int j = 0; j < 4; ++j)
#pragma unroll
            for (int r = 0; r < 4; ++r) acc[i][j][r] = 0.f;

#pragma unroll
    for (int ks = 0; ks < 4; ++ks) {
        s16x8 af[2];
#pragma unroll
        for (int i = 0; i < 2; ++i) {
            int row = (wr << 5) + (i << 4) + lr;
            int cb = (ks << 3) + (lk << 1);
            int c0 = cb ^ (row & 7), c1 = (cb + 1) ^ (row & 7);
            f32x4 x0 = *(const f32x4*)&sf[row * 128 + (c0 << 2)];
            f32x4 x1 = *(const f32x4*)&sf[row * 128 + (c1 << 2)];
            s16x8 a;
            a[0] = f2bf(x0[0]); a[1] = f2bf(x0[1]); a[2] = f2bf(x0[2]); a[3] = f2bf(x0[3]);
            a[4] = f2bf(x1[0]); a[5] = f2bf(x1[1]); a[6] = f2bf(x1[2]); a[7] = f2bf(x1[3]);
            af[i] = a;
        }
#pragma unroll
        for (int j = 0; j < 4; ++j) {
            int f = (wc << 6) + (j << 4) + lr;
            s16x8 bfr = *(const s16x8*)&swt[((((ks << 2) | lk) << 7) | f) << 3];
#pragma unroll
            for (int i = 0; i < 2; ++i)
                acc[i][j] = __builtin_amdgcn_mfma_f32_16x16x32_bf16(af[i], bfr, acc[i][j], 0, 0, 0);
        }
    }

    // epilogue: scale by dis[m], store to fwdT in k3 order
#pragma unroll
    for (int i = 0; i < 2; ++i) {
        int mr = (wr << 5) + (i << 4) + (lk << 2);
        f32x4 d4 = *(const f32x4*)&dis[m0 + mr];
        int mg = ml0 + mr;
        int ktm = mg >> 5, q3 = (mg >> 3) & 3, jm = mg & 7;
#pragma unroll
        for (int j = 0; j < 4; ++j) {
            int f = (wc << 6) + (j << 4) + lr;
            u16x4 o;
            o[0] = f2bf(d4[0] * acc[i][j][0]);
            o[1] = f2bf(d4[1] * acc[i][j][1]);
            o[2] = f2bf(d4[2] * acc[i][j][2]);
            o[3] = f2bf(d4[3] * acc[i][j][3]);
            *(u16x4*)((char*)fwdT + ((size_t)b << 17) + (((ktm << 2) | q3) << 11)
                      + (f << 4) + (jm << 1)) = o;
        }
    }
}

// ---------------------------------------------------------------------------
// k3: out[b,n,512+f] = relu( dis[n] * (A[n,:] @ featWD[:,f] + featWD[n,f]) )
// block = 64 rows x 128 f; 4 waves each own 16 rows x 128 f.
// A: per-lane direct global->VGPR from LINEAR Abf (row*1024 + kt*64 + lk*16;
//    wave = 16 rows x 64B contiguous), prefetched one phase ahead.
// B: double-buffered LDS, BK=64 (2 kt per phase), linear glds16 staging.
// ---------------------------------------------------------------------------
__global__ __launch_bounds__(256) void k3_gcn(const unsigned short* __restrict__ Abf,
                                              const float* __restrict__ dis,
                                              const unsigned short* __restrict__ fwdT,
                                              float* __restrict__ out) {
    __shared__ __align__(16) unsigned short sb[2][8192];    // 16KB per buf
    const int t = threadIdx.x, l = t & 63, wv = t >> 6, lr = l & 15, lk = l >> 4;
    const int b = blockIdx.x >> 3, bm0 = (blockIdx.x & 7) << 6;
    const char* Bt = (const char*)fwdT + ((size_t)b << 17);
    // lane-resolved A pointer: row = b*512 + bm0 + wv*16 + lr, chunk lk
    const char* Ab = (const char*)Abf
        + (((size_t)(b * GS + bm0 + (wv << 4) + lr)) << 10) + (lk << 4);

    auto stage = [&](int buf, int ph) {
#pragma unroll
        for (int it = 0; it < 4; ++it)                       // 16KB = 2 kt-tiles
            glds16(Bt + (ph << 14) + it * 4096 + wv * 1024 + l * 16,
                   (char*)sb[buf] + it * 4096 + wv * 1024);
    };

    f32x4 acc[8];
#pragma unroll
    for (int j = 0; j < 8; ++j)
#pragma unroll
        for (int r = 0; r < 4; ++r) acc[j][r] = 0.f;

    stage(0, 0);
    s16x8 a0 = *(const s16x8*)(Ab);
    s16x8 a1 = *(const s16x8*)(Ab + 64);
    int cur = 0;
    for (int ph = 0; ph < 8; ++ph) {
        __syncthreads();                                     // drains staging vmcnt
        if (ph < 7) stage(cur ^ 1, ph + 1);
        s16x8 n0 = a0, n1 = a1;
        if (ph < 7) {
            n0 = *(const s16x8*)(Ab + ((2 * ph + 2) << 6));
            n1 = *(const s16x8*)(Ab + ((2 * ph + 3) << 6));
        }
        __builtin_amdgcn_s_setprio(1);
#pragma unroll
        for (int j = 0; j < 8; ++j) {
            s16x8 bfr = *(const s16x8*)&sb[cur][(lk << 10) + (j << 7) + (lr << 3)];
            acc[j] = __builtin_amdgcn_mfma_f32_16x16x32_bf16(a0, bfr, acc[j], 0, 0, 0);
        }
#pragma unroll
        for (int j = 0; j < 8; ++j) {
            s16x8 bfr = *(const s16x8*)&sb[cur][4096 + (lk << 10) + (j << 7) + (lr << 3)];
            acc[j] = __builtin_amdgcn_mfma_f32_16x16x32_bf16(a1, bfr, acc[j], 0, 0, 0);
        }
        __builtin_amdgcn_s_setprio(0);
        a0 = n0; a1 = n1; cur ^= 1;
    }

    // epilogue: + identity featWD[n,f], * dis[n], relu, store fp32
    const int n0r = bm0 + (wv << 4) + (lk << 2);            // base of 4 rows
    f32x4 d4 = *(const f32x4*)&dis[(b << 9) + n0r];
    const int ktm = n0r >> 5, q3 = (n0r >> 3) & 3, jm = n0r & 7;
#pragma unroll
    for (int j = 0; j < 8; ++j) {
        int f = (j << 4) + lr;
        u16x4 fw = *(const u16x4*)(Bt + (((ktm << 2) | q3) << 11) + (f << 4) + (jm << 1));
        float* ob = out + ((size_t)(b * GS + n0r)) * XROW + GS + f;
#pragma unroll
        for (int r = 0; r < 4; ++r) {
            float v = d4[r] * (acc[j][r] + bf2f(fw[r]));
            ob[(size_t)r * XROW] = v > 0.f ? v : 0.f;
        }
    }
}

extern "C" void kernel_launch(void* const* d_in, const int* in_sizes, int n_in,
                              void* d_out, int out_size, void* d_ws, size_t ws_size,
                              hipStream_t stream) {
    const float* X = (const float*)d_in[0];
    const float* W = (const float*)d_in[1];
    float* out = (float*)d_out;
    // ws layout (bytes):
    float*          dis  = (float*)d_ws;                                  // 262144
    unsigned short* WTst = (unsigned short*)((char*)d_ws + 262144);       // 32768
    unsigned short* fwdT = (unsigned short*)((char*)d_ws + 294912);       // 16 MiB
    unsigned short* Abf  = (unsigned short*)((char*)d_ws + 17072128);     // 64 MiB

    hipLaunchKernelGGL(k0_wt,   dim3(64),   dim3(256), 0, stream, W, WTst);
    hipLaunchKernelGGL(k1_pre,  dim3(NB * GS / 8),  dim3(256), 0, stream, X, out, dis, Abf);
    hipLaunchKernelGGL(k2_featw, dim3(NB * GS / 64), dim3(256), 0, stream, X, WTst, dis, fwdT);
    hipLaunchKernelGGL(k3_gcn,  dim3(NB * GS / 64), dim3(256), 0, stream, Abf, dis, fwdT, out);
}